// Round 1
// baseline (2143.528 us; speedup 1.0000x reference)
//
#include <hip/hip_runtime.h>
#include <math.h>

#define NS   4      // batch
#define CH   128    // channels
#define HW   96     // full-res H=W
#define GS   48     // half-res grid side
#define LL   2304   // GS*GS
#define CKN  2048   // CH*16 (4x4 taps)
#define SCALE 10.0f
#define EPSSUM 0.1152f  // 1152 * 1e-4
#define PCH  128    // softmax p-chunk
#define NCHUNK 18   // 2304/128

// ---------------- staging ----------------

// bs_c[c][rs] = b[c, 2r, 2s]; fs_c[c][rs] = f[c, 2r, 2s]
__global__ __launch_bounds__(256) void k_stage(const float* __restrict__ b, const float* __restrict__ f,
                                               float* __restrict__ bs_c, float* __restrict__ fs_c) {
    int c  = blockIdx.y;
    int rs = blockIdx.x * 256 + threadIdx.x;     // gridDim.x = 9
    int r = rs / GS, s = rs % GS;
    int src = c * HW * HW + (2 * r) * HW + 2 * s;
    bs_c[c * LL + rs] = b[src];
    fs_c[c * LL + rs] = f[src];
}

// ssq[rs] = sum_c bs_c[c][rs]^2
__global__ __launch_bounds__(256) void k_ssq(const float* __restrict__ bs_c, float* __restrict__ ssq) {
    int rs = blockIdx.x * 256 + threadIdx.x;
    float acc = 0.f;
    for (int c = 0; c < CH; ++c) { float v = bs_c[c * LL + rs]; acc += v * v; }
    ssq[rs] = acc;
}

// invn[p] = 1/sqrt(sum_{3x3} ssq + 1152*EPS); mmv[p] from mask (patch mean == 1)
__global__ __launch_bounds__(256) void k_norm_mm(const float* __restrict__ ssq, const float* __restrict__ mk,
                                                 float* __restrict__ invn, float* __restrict__ mmv) {
    int p = blockIdx.x * 256 + threadIdx.x;
    int ph = p / GS, pw = p % GS;
    float acc = EPSSUM;
    float msum = 0.f;
    for (int di = -1; di <= 1; ++di)
        for (int dj = -1; dj <= 1; ++dj) {
            int r = ph + di, s = pw + dj;
            if (r >= 0 && r < GS && s >= 0 && s < GS) {
                acc  += ssq[r * GS + s];
                msum += mk[(2 * r) * HW + 2 * s];
            }
        }
    invn[p] = 1.0f / sqrtf(acc);
    mmv[p]  = (msum / 9.0f == 1.0f) ? 1.0f : 0.0f;
}

// W2[p][c*16+dy*4+dx] = b[c, 2ph+dy-1, 2pw+dx-1] (0 if OOB)
__global__ __launch_bounds__(256) void k_w2(const float* __restrict__ b, float* __restrict__ W2) {
    int p  = blockIdx.y;
    int ck = blockIdx.x * 256 + threadIdx.x;     // gridDim.x = 8
    int ph = p / GS, pw = p % GS;
    int c = ck >> 4, dy = (ck >> 2) & 3, dx = ck & 3;
    int r = 2 * ph + dy - 1, s = 2 * pw + dx - 1;
    float v = 0.f;
    if (r >= 0 && r < HW && s >= 0 && s < HW) v = b[c * HW * HW + r * HW + s];
    W2[p * CKN + ck] = v;
}

// ---------------- generic TN GEMM: C[m][n] = sum_k A[k][m]*B[k][n] ----------------
// A: [K][M] row-major, B: [K][N] row-major, C: [M][N] row-major.
// M,N multiples of 64; K multiple of 16.
__global__ __launch_bounds__(256) void gemm_tn(const float* __restrict__ A, const float* __restrict__ B,
                                               float* __restrict__ C, int M, int N, int K) {
    __shared__ float As[16][64];
    __shared__ float Bs[16][64];
    int t  = threadIdx.x;
    int tx = t & 15, ty = t >> 4;
    int m0 = blockIdx.y * 64, n0 = blockIdx.x * 64;
    float acc[4][4] = {{0.f}};
    for (int k0 = 0; k0 < K; k0 += 16) {
#pragma unroll
        for (int i = 0; i < 4; ++i) {
            int e  = t + i * 256;
            int kk = e >> 6, mm = e & 63;
            As[kk][mm] = A[(size_t)(k0 + kk) * M + m0 + mm];
            Bs[kk][mm] = B[(size_t)(k0 + kk) * N + n0 + mm];
        }
        __syncthreads();
#pragma unroll
        for (int k = 0; k < 16; ++k) {
            float4 av = *reinterpret_cast<const float4*>(&As[k][ty * 4]);
            float4 bv = *reinterpret_cast<const float4*>(&Bs[k][tx * 4]);
            float ar[4] = {av.x, av.y, av.z, av.w};
            float br[4] = {bv.x, bv.y, bv.z, bv.w};
#pragma unroll
            for (int r = 0; r < 4; ++r)
#pragma unroll
                for (int cc = 0; cc < 4; ++cc)
                    acc[r][cc] = fmaf(ar[r], br[cc], acc[r][cc]);
        }
        __syncthreads();
    }
#pragma unroll
    for (int r = 0; r < 4; ++r)
#pragma unroll
        for (int cc = 0; cc < 4; ++cc)
            C[(size_t)(m0 + ty * 4 + r) * N + n0 + tx * 4 + cc] = acc[r][cc];
}

// ---------------- correlation assembly + fuses ----------------

// yi[p][q] = invn[p] * sum_{di,dj in [-1,1]} D[(ph+di,pw+dj)][(qh+di,qw+dj)]
__global__ __launch_bounds__(256) void k_corr(const float* __restrict__ D, const float* __restrict__ invn,
                                              float* __restrict__ yi) {
    int p = blockIdx.y;
    int q = blockIdx.x * 256 + threadIdx.x;
    int ph = p / GS, pw = p % GS, qh = q / GS, qw = q % GS;
    float s = 0.f;
#pragma unroll
    for (int di = -1; di <= 1; ++di) {
        int rp = ph + di, tq = qh + di;
        if (rp < 0 || rp >= GS || tq < 0 || tq >= GS) continue;
#pragma unroll
        for (int dj = -1; dj <= 1; ++dj) {
            int sp = pw + dj, uq = qw + dj;
            if (sp < 0 || sp >= GS || uq < 0 || uq >= GS) continue;
            s += D[(size_t)(rp * GS + sp) * LL + (tq * GS + uq)];
        }
    }
    yi[(size_t)p * LL + q] = invn[p] * s;
}

// S1[a][b] = sum_{d=-1..1} yi[a+d][b+d]  (flat indices, zero pad)
__global__ __launch_bounds__(256) void k_fuse1(const float* __restrict__ yi, float* __restrict__ S1) {
    int a = blockIdx.y;
    int bcol = blockIdx.x * 256 + threadIdx.x;
    float s = 0.f;
#pragma unroll
    for (int d = -1; d <= 1; ++d) {
        int aa = a + d, bb = bcol + d;
        if (aa >= 0 && aa < LL && bb >= 0 && bb < LL) s += yi[(size_t)aa * LL + bb];
    }
    S1[(size_t)a * LL + bcol] = s;
}

__device__ __forceinline__ int gmap(int x) { int hi = x / GS; int lo = x - hi * GS; return lo * GS + hi; }

// S2[p][q] = sum_{e=-1..1} S1[gmap(pw*48+ph+e)][gmap(qw*48+qh+e)]  (flat bounds on pre-gmap index)
__global__ __launch_bounds__(256) void k_fuse2(const float* __restrict__ S1, float* __restrict__ S2) {
    int p = blockIdx.y;
    int q = blockIdx.x * 256 + threadIdx.x;
    int ph = p / GS, pw = p % GS, qh = q / GS, qw = q % GS;
    int a0 = pw * GS + ph, b0 = qw * GS + qh;
    float s = 0.f;
#pragma unroll
    for (int e = -1; e <= 1; ++e) {
        int ae = a0 + e, be = b0 + e;
        if (ae >= 0 && ae < LL && be >= 0 && be < LL)
            s += S1[(size_t)gmap(ae) * LL + gmap(be)];
    }
    S2[(size_t)p * LL + q] = s;
}

// ---------------- softmax over p (3-stage, chunked) ----------------

__global__ __launch_bounds__(256) void k_sm1(const float* __restrict__ S2, const float* __restrict__ mmv,
                                             float* __restrict__ pmax, float* __restrict__ psum) {
    int q  = blockIdx.x * 256 + threadIdx.x;
    int p0 = blockIdx.y * PCH;
    float mx = -1e30f;
    for (int p = p0; p < p0 + PCH; ++p) {
        float lg = (mmv[p] != 0.f) ? SCALE * S2[(size_t)p * LL + q] : 0.f;
        mx = fmaxf(mx, lg);
    }
    float sm = 0.f;
    for (int p = p0; p < p0 + PCH; ++p) {
        float lg = (mmv[p] != 0.f) ? SCALE * S2[(size_t)p * LL + q] : 0.f;
        sm += expf(lg - mx);
    }
    pmax[blockIdx.y * LL + q] = mx;
    psum[blockIdx.y * LL + q] = sm;
}

__global__ __launch_bounds__(256) void k_sm2(const float* __restrict__ pmax, const float* __restrict__ psum,
                                             float* __restrict__ Mq, float* __restrict__ Dq) {
    int q = blockIdx.x * 256 + threadIdx.x;
    float mx = -1e30f;
    for (int ch = 0; ch < NCHUNK; ++ch) mx = fmaxf(mx, pmax[ch * LL + q]);
    float den = 0.f;
    for (int ch = 0; ch < NCHUNK; ++ch) den += psum[ch * LL + q] * expf(pmax[ch * LL + q] - mx);
    Mq[q] = mx; Dq[q] = den;
}

// in-place: S2[p][q] = mmv[p] * exp(10*v - Mq)/Dq
__global__ __launch_bounds__(256) void k_sm3(float* __restrict__ S2, const float* __restrict__ mmv,
                                             const float* __restrict__ Mq, const float* __restrict__ Dq) {
    int p = blockIdx.y;
    int q = blockIdx.x * 256 + threadIdx.x;
    float v = S2[(size_t)p * LL + q];
    float attn = (mmv[p] != 0.f) ? expf(SCALE * v - Mq[q]) / Dq[q] : 0.f;
    S2[(size_t)p * LL + q] = attn;
}

// ---------------- output assembly ----------------
// out[c, 2u+a, 2v+w] = 0.25 * sum of 4 taps of Z[q][c*16+dy*4+dx]
__global__ __launch_bounds__(256) void k_out(const float* __restrict__ Z, float* __restrict__ out) {
    int c  = blockIdx.y;
    int yx = blockIdx.x * 256 + threadIdx.x;     // gridDim.x = 36
    int y = yx / HW, x = yx % HW;
    int u = y >> 1, a = y & 1, v = x >> 1, w = x & 1;
    int qh1 = u + a - 1, qh2 = u + a, qw1 = v + w - 1, qw2 = v + w;
    int cb = c * 16;
    float s = 0.f;
    if (qh1 >= 0) {
        if (qw1 >= 0)  s += Z[(size_t)(qh1 * GS + qw1) * CKN + cb + (3 - a) * 4 + (3 - w)];
        if (qw2 < GS)  s += Z[(size_t)(qh1 * GS + qw2) * CKN + cb + (3 - a) * 4 + (1 - w)];
    }
    if (qh2 < GS) {
        if (qw1 >= 0)  s += Z[(size_t)(qh2 * GS + qw1) * CKN + cb + (1 - a) * 4 + (3 - w)];
        if (qw2 < GS)  s += Z[(size_t)(qh2 * GS + qw2) * CKN + cb + (1 - a) * 4 + (1 - w)];
    }
    out[(size_t)c * HW * HW + yx] = 0.25f * s;
}

// ---------------- launch ----------------

extern "C" void kernel_launch(void* const* d_in, const int* in_sizes, int n_in,
                              void* d_out, int out_size, void* d_ws, size_t ws_size,
                              hipStream_t stream) {
    const float* b_all = (const float*)d_in[0];
    const float* f_all = (const float*)d_in[1];
    const float* m_all = (const float*)d_in[2];
    float* out = (float*)d_out;
    float* ws  = (float*)d_ws;

    size_t off = 0;
    float* bs_c = ws + off; off += (size_t)CH * LL;
    float* fs_c = ws + off; off += (size_t)CH * LL;
    float* ssq  = ws + off; off += LL;
    float* invn = ws + off; off += LL;
    float* mmv  = ws + off; off += LL;
    float* Mq   = ws + off; off += LL;
    float* Dq   = ws + off; off += LL;
    float* pmax = ws + off; off += (size_t)NCHUNK * LL;
    float* psum = ws + off; off += (size_t)NCHUNK * LL;
    float* bufA = ws + off; off += (size_t)LL * LL;   // D -> S1 -> Z
    float* bufB = ws + off; off += (size_t)LL * LL;   // yi -> S2 -> attn
    float* W2   = ws + off; off += (size_t)LL * CKN;

    for (int i = 0; i < NS; ++i) {
        const float* b  = b_all + (size_t)i * CH * HW * HW;
        const float* f  = f_all + (size_t)i * CH * HW * HW;
        const float* mk = m_all + (size_t)i * HW * HW;
        float* outp = out + (size_t)i * CH * HW * HW;

        k_stage  <<<dim3(9, CH), 256, 0, stream>>>(b, f, bs_c, fs_c);
        k_ssq    <<<9, 256, 0, stream>>>(bs_c, ssq);
        k_norm_mm<<<9, 256, 0, stream>>>(ssq, mk, invn, mmv);
        k_w2     <<<dim3(8, LL), 256, 0, stream>>>(b, W2);

        // D = bs^T fs : [2304 x 2304], K=128
        gemm_tn  <<<dim3(36, 36), 256, 0, stream>>>(bs_c, fs_c, bufA, LL, LL, CH);
        k_corr   <<<dim3(9, LL), 256, 0, stream>>>(bufA, invn, bufB);
        k_fuse1  <<<dim3(9, LL), 256, 0, stream>>>(bufB, bufA);
        k_fuse2  <<<dim3(9, LL), 256, 0, stream>>>(bufA, bufB);

        k_sm1    <<<dim3(9, NCHUNK), 256, 0, stream>>>(bufB, mmv, pmax, psum);
        k_sm2    <<<9, 256, 0, stream>>>(pmax, psum, Mq, Dq);
        k_sm3    <<<dim3(9, LL), 256, 0, stream>>>(bufB, mmv, Mq, Dq);

        // Z = attn^T-contract : [2304 x 2048], K=2304
        gemm_tn  <<<dim3(32, 36), 256, 0, stream>>>(bufB, W2, bufA, LL, CKN, LL);
        k_out    <<<dim3(36, CH), 256, 0, stream>>>(bufA, outp);
    }
}

// Round 2
// 1178.950 us; speedup vs baseline: 1.8182x; 1.8182x over previous
//
#include <hip/hip_runtime.h>
#include <hip/hip_bf16.h>
#include <math.h>

#define NS   4      // batch
#define CH   128    // channels
#define HW   96     // full-res H=W
#define GS   48     // half-res grid side
#define LL   2304   // GS*GS
#define CKN  2048   // CH*16 (4x4 taps)
#define SCALE 10.0f
#define EPSSUM 0.1152f  // 1152 * 1e-4
#define PCH  128    // softmax p-chunk
#define NCHUNK 18   // 2304/128

typedef __attribute__((ext_vector_type(8))) short short8;
typedef __attribute__((ext_vector_type(4))) float float4v;

// ---------------- staging ----------------

__global__ __launch_bounds__(256) void k_stage(const float* __restrict__ b, const float* __restrict__ f,
                                               float* __restrict__ bs_c, float* __restrict__ fs_c) {
    int c  = blockIdx.y;
    int rs = blockIdx.x * 256 + threadIdx.x;     // gridDim.x = 9
    int r = rs / GS, s = rs % GS;
    int src = c * HW * HW + (2 * r) * HW + 2 * s;
    bs_c[c * LL + rs] = b[src];
    fs_c[c * LL + rs] = f[src];
}

__global__ __launch_bounds__(256) void k_ssq(const float* __restrict__ bs_c, float* __restrict__ ssq) {
    int rs = blockIdx.x * 256 + threadIdx.x;
    float acc = 0.f;
    for (int c = 0; c < CH; ++c) { float v = bs_c[c * LL + rs]; acc += v * v; }
    ssq[rs] = acc;
}

__global__ __launch_bounds__(256) void k_norm_mm(const float* __restrict__ ssq, const float* __restrict__ mk,
                                                 float* __restrict__ invn, float* __restrict__ mmv) {
    int p = blockIdx.x * 256 + threadIdx.x;
    int ph = p / GS, pw = p % GS;
    float acc = EPSSUM;
    float msum = 0.f;
    for (int di = -1; di <= 1; ++di)
        for (int dj = -1; dj <= 1; ++dj) {
            int r = ph + di, s = pw + dj;
            if (r >= 0 && r < GS && s >= 0 && s < GS) {
                acc  += ssq[r * GS + s];
                msum += mk[(2 * r) * HW + 2 * s];
            }
        }
    invn[p] = 1.0f / sqrtf(acc);
    mmv[p]  = (msum / 9.0f == 1.0f) ? 1.0f : 0.0f;
}

// W2T[ck][p] = bf16( b[c, 2ph+dy-1, 2pw+dx-1] ), ck = c*16+dy*4+dx
__global__ __launch_bounds__(256) void k_w2T(const float* __restrict__ b, __hip_bfloat16* __restrict__ W2T) {
    int ck = blockIdx.y;                         // 0..2047
    int p  = blockIdx.x * 256 + threadIdx.x;     // gridDim.x = 9
    int c = ck >> 4, dy = (ck >> 2) & 3, dx = ck & 3;
    int ph = p / GS, pw = p % GS;
    int r = 2 * ph + dy - 1, s = 2 * pw + dx - 1;
    float v = 0.f;
    if (r >= 0 && r < HW && s >= 0 && s < HW) v = b[c * HW * HW + r * HW + s];
    W2T[(size_t)ck * LL + p] = __float2bfloat16(v);
}

// ---------------- fp32 TN GEMM (GEMM1 only): C[m][n] = sum_k A[k][m]*B[k][n] ----------------
__global__ __launch_bounds__(256) void gemm_tn(const float* __restrict__ A, const float* __restrict__ B,
                                               float* __restrict__ C, int M, int N, int K) {
    __shared__ float As[16][64];
    __shared__ float Bs[16][64];
    int t  = threadIdx.x;
    int tx = t & 15, ty = t >> 4;
    int m0 = blockIdx.y * 64, n0 = blockIdx.x * 64;
    float acc[4][4] = {{0.f}};
    for (int k0 = 0; k0 < K; k0 += 16) {
#pragma unroll
        for (int i = 0; i < 4; ++i) {
            int e  = t + i * 256;
            int kk = e >> 6, mm = e & 63;
            As[kk][mm] = A[(size_t)(k0 + kk) * M + m0 + mm];
            Bs[kk][mm] = B[(size_t)(k0 + kk) * N + n0 + mm];
        }
        __syncthreads();
#pragma unroll
        for (int k = 0; k < 16; ++k) {
            float4 av = *reinterpret_cast<const float4*>(&As[k][ty * 4]);
            float4 bv = *reinterpret_cast<const float4*>(&Bs[k][tx * 4]);
            float ar[4] = {av.x, av.y, av.z, av.w};
            float br[4] = {bv.x, bv.y, bv.z, bv.w};
#pragma unroll
            for (int r = 0; r < 4; ++r)
#pragma unroll
                for (int cc = 0; cc < 4; ++cc)
                    acc[r][cc] = fmaf(ar[r], br[cc], acc[r][cc]);
        }
        __syncthreads();
    }
#pragma unroll
    for (int r = 0; r < 4; ++r)
#pragma unroll
        for (int cc = 0; cc < 4; ++cc)
            C[(size_t)(m0 + ty * 4 + r) * N + n0 + tx * 4 + cc] = acc[r][cc];
}

// ---------------- bf16 MFMA GEMM (GEMM2): C[m][n] = sum_k A[m][k]*B[n][k] ----------------
// A: [M][K] row-major bf16 (attnT), B: [N][K] row-major bf16 (W2T), C: [M][N] fp32.
// 128x128 tile, BK=32, 4 waves of 64x64, global_load_lds width 16.
__global__ __launch_bounds__(256) void gemm2_mfma(const __hip_bfloat16* __restrict__ A,
                                                  const __hip_bfloat16* __restrict__ B,
                                                  float* __restrict__ C, int M, int N, int K) {
    __shared__ __hip_bfloat16 As[128 * 32];
    __shared__ __hip_bfloat16 Bs[128 * 32];
    int t = threadIdx.x;
    int lane = t & 63, w = t >> 6;
    int wr = w >> 1, wc = w & 1;                 // 2x2 waves -> 64x64 each
    int m0 = blockIdx.y * 128, n0 = blockIdx.x * 128;

    float4v acc[4][4];
#pragma unroll
    for (int i = 0; i < 4; ++i)
#pragma unroll
        for (int j = 0; j < 4; ++j) acc[i][j] = (float4v){0.f, 0.f, 0.f, 0.f};

    for (int k0 = 0; k0 < K; k0 += 32) {
        // stage: 128 rows x 32 bf16 = 8192 B = 512 x 16B chunks per matrix; 2 chunks/thread
#pragma unroll
        for (int it = 0; it < 2; ++it) {
            int chunk = it * 256 + w * 64 + lane;    // contiguous 64-chunk run per wave
            int row = chunk >> 2, part = chunk & 3;
            const __hip_bfloat16* ga = A + (size_t)(m0 + row) * K + k0 + part * 8;
            const __hip_bfloat16* gb = B + (size_t)(n0 + row) * K + k0 + part * 8;
            __builtin_amdgcn_global_load_lds((const __attribute__((address_space(1))) void*)ga,
                 (__attribute__((address_space(3))) void*)((char*)As + (size_t)chunk * 16), 16, 0, 0);
            __builtin_amdgcn_global_load_lds((const __attribute__((address_space(1))) void*)gb,
                 (__attribute__((address_space(3))) void*)((char*)Bs + (size_t)chunk * 16), 16, 0, 0);
        }
        __syncthreads();

        int lrow = lane & 15, lk = (lane >> 4) * 8;
        short8 afrag[4], bfrag[4];
#pragma unroll
        for (int i = 0; i < 4; ++i)
            afrag[i] = *reinterpret_cast<const short8*>(As + (wr * 64 + i * 16 + lrow) * 32 + lk);
#pragma unroll
        for (int j = 0; j < 4; ++j)
            bfrag[j] = *reinterpret_cast<const short8*>(Bs + (wc * 64 + j * 16 + lrow) * 32 + lk);
#pragma unroll
        for (int i = 0; i < 4; ++i)
#pragma unroll
            for (int j = 0; j < 4; ++j)
                acc[i][j] = __builtin_amdgcn_mfma_f32_16x16x32_bf16(afrag[i], bfrag[j], acc[i][j], 0, 0, 0);
        __syncthreads();
    }

    // C/D layout: col = lane&15, row = (lane>>4)*4 + reg
    int col = lane & 15, rbase = (lane >> 4) * 4;
#pragma unroll
    for (int i = 0; i < 4; ++i)
#pragma unroll
        for (int j = 0; j < 4; ++j)
#pragma unroll
            for (int r = 0; r < 4; ++r) {
                int m = m0 + wr * 64 + i * 16 + rbase + r;
                int n = n0 + wc * 64 + j * 16 + col;
                C[(size_t)m * N + n] = acc[i][j][r];
            }
}

// ---------------- correlation assembly + fuses ----------------

__global__ __launch_bounds__(256) void k_corr(const float* __restrict__ D, const float* __restrict__ invn,
                                              float* __restrict__ yi) {
    int p = blockIdx.y;
    int q = blockIdx.x * 256 + threadIdx.x;
    int ph = p / GS, pw = p % GS, qh = q / GS, qw = q % GS;
    float s = 0.f;
#pragma unroll
    for (int di = -1; di <= 1; ++di) {
        int rp = ph + di, tq = qh + di;
        if (rp < 0 || rp >= GS || tq < 0 || tq >= GS) continue;
#pragma unroll
        for (int dj = -1; dj <= 1; ++dj) {
            int sp = pw + dj, uq = qw + dj;
            if (sp < 0 || sp >= GS || uq < 0 || uq >= GS) continue;
            s += D[(size_t)(rp * GS + sp) * LL + (tq * GS + uq)];
        }
    }
    yi[(size_t)p * LL + q] = invn[p] * s;
}

__global__ __launch_bounds__(256) void k_fuse1(const float* __restrict__ yi, float* __restrict__ S1) {
    int a = blockIdx.y;
    int bcol = blockIdx.x * 256 + threadIdx.x;
    float s = 0.f;
#pragma unroll
    for (int d = -1; d <= 1; ++d) {
        int aa = a + d, bb = bcol + d;
        if (aa >= 0 && aa < LL && bb >= 0 && bb < LL) s += yi[(size_t)aa * LL + bb];
    }
    S1[(size_t)a * LL + bcol] = s;
}

__device__ __forceinline__ int gmap(int x) { int hi = x / GS; int lo = x - hi * GS; return lo * GS + hi; }

__global__ __launch_bounds__(256) void k_fuse2(const float* __restrict__ S1, float* __restrict__ S2) {
    int p = blockIdx.y;
    int q = blockIdx.x * 256 + threadIdx.x;
    int ph = p / GS, pw = p % GS, qh = q / GS, qw = q % GS;
    int a0 = pw * GS + ph, b0 = qw * GS + qh;
    float s = 0.f;
#pragma unroll
    for (int e = -1; e <= 1; ++e) {
        int ae = a0 + e, be = b0 + e;
        if (ae >= 0 && ae < LL && be >= 0 && be < LL)
            s += S1[(size_t)gmap(ae) * LL + gmap(be)];
    }
    S2[(size_t)p * LL + q] = s;
}

// ---------------- softmax over p ----------------

__global__ __launch_bounds__(256) void k_sm1(const float* __restrict__ S2, const float* __restrict__ mmv,
                                             float* __restrict__ pmax, float* __restrict__ psum) {
    int q  = blockIdx.x * 256 + threadIdx.x;
    int p0 = blockIdx.y * PCH;
    float mx = -1e30f;
    for (int p = p0; p < p0 + PCH; ++p) {
        float lg = (mmv[p] != 0.f) ? SCALE * S2[(size_t)p * LL + q] : 0.f;
        mx = fmaxf(mx, lg);
    }
    float sm = 0.f;
    for (int p = p0; p < p0 + PCH; ++p) {
        float lg = (mmv[p] != 0.f) ? SCALE * S2[(size_t)p * LL + q] : 0.f;
        sm += expf(lg - mx);
    }
    pmax[blockIdx.y * LL + q] = mx;
    psum[blockIdx.y * LL + q] = sm;
}

__global__ __launch_bounds__(256) void k_sm2(const float* __restrict__ pmax, const float* __restrict__ psum,
                                             float* __restrict__ Mq, float* __restrict__ Dq) {
    int q = blockIdx.x * 256 + threadIdx.x;
    float mx = -1e30f;
    for (int ch = 0; ch < NCHUNK; ++ch) mx = fmaxf(mx, pmax[ch * LL + q]);
    float den = 0.f;
    for (int ch = 0; ch < NCHUNK; ++ch) den += psum[ch * LL + q] * expf(pmax[ch * LL + q] - mx);
    Mq[q] = mx; Dq[q] = den;
}

// attnT[q][p] = bf16( mmv[p] * exp(10*S2[p][q] - Mq[q]) / Dq[q] ) via 32x32 LDS transpose
__global__ __launch_bounds__(256) void k_sm3T(const float* __restrict__ S2, const float* __restrict__ mmv,
                                              const float* __restrict__ Mq, const float* __restrict__ Dq,
                                              __hip_bfloat16* __restrict__ attnT) {
    __shared__ float tile[32][33];
    int tx = threadIdx.x & 31, ty = threadIdx.x >> 5;    // ty 0..7
    int p0 = blockIdx.y * 32, q0 = blockIdx.x * 32;
    int q = q0 + tx;
    float mq = Mq[q], dq = Dq[q];
#pragma unroll
    for (int j = 0; j < 4; ++j) {
        int p = p0 + ty + 8 * j;
        float v = S2[(size_t)p * LL + q];
        float attn = (mmv[p] != 0.f) ? expf(SCALE * v - mq) / dq : 0.f;
        tile[ty + 8 * j][tx] = attn;
    }
    __syncthreads();
#pragma unroll
    for (int j = 0; j < 4; ++j) {
        int qq = q0 + ty + 8 * j;
        attnT[(size_t)qq * LL + p0 + tx] = __float2bfloat16(tile[tx][ty + 8 * j]);
    }
}

// ---------------- output assembly ----------------
__global__ __launch_bounds__(256) void k_out(const float* __restrict__ Z, float* __restrict__ out) {
    int c  = blockIdx.y;
    int yx = blockIdx.x * 256 + threadIdx.x;     // gridDim.x = 36
    int y = yx / HW, x = yx % HW;
    int u = y >> 1, a = y & 1, v = x >> 1, w = x & 1;
    int qh1 = u + a - 1, qh2 = u + a, qw1 = v + w - 1, qw2 = v + w;
    int cb = c * 16;
    float s = 0.f;
    if (qh1 >= 0) {
        if (qw1 >= 0)  s += Z[(size_t)(qh1 * GS + qw1) * CKN + cb + (3 - a) * 4 + (3 - w)];
        if (qw2 < GS)  s += Z[(size_t)(qh1 * GS + qw2) * CKN + cb + (3 - a) * 4 + (1 - w)];
    }
    if (qh2 < GS) {
        if (qw1 >= 0)  s += Z[(size_t)(qh2 * GS + qw1) * CKN + cb + (1 - a) * 4 + (3 - w)];
        if (qw2 < GS)  s += Z[(size_t)(qh2 * GS + qw2) * CKN + cb + (1 - a) * 4 + (1 - w)];
    }
    out[(size_t)c * HW * HW + yx] = 0.25f * s;
}

// ---------------- launch ----------------

extern "C" void kernel_launch(void* const* d_in, const int* in_sizes, int n_in,
                              void* d_out, int out_size, void* d_ws, size_t ws_size,
                              hipStream_t stream) {
    const float* b_all = (const float*)d_in[0];
    const float* f_all = (const float*)d_in[1];
    const float* m_all = (const float*)d_in[2];
    float* out = (float*)d_out;
    float* ws  = (float*)d_ws;

    size_t off = 0;
    float* bs_c = ws + off; off += (size_t)CH * LL;
    float* fs_c = ws + off; off += (size_t)CH * LL;
    float* ssq  = ws + off; off += LL;
    float* invn = ws + off; off += LL;
    float* mmv  = ws + off; off += LL;
    float* Mq   = ws + off; off += LL;
    float* Dq   = ws + off; off += LL;
    float* pmax = ws + off; off += (size_t)NCHUNK * LL;
    float* psum = ws + off; off += (size_t)NCHUNK * LL;
    float* bufA = ws + off; off += (size_t)LL * LL;   // D -> S1 -> Z
    float* bufB = ws + off; off += (size_t)LL * LL;   // yi -> S2
    __hip_bfloat16* W2T   = (__hip_bfloat16*)(ws + off); off += (size_t)CKN * LL / 2;
    __hip_bfloat16* attnT = (__hip_bfloat16*)(ws + off); off += (size_t)LL * LL / 2;

    for (int i = 0; i < NS; ++i) {
        const float* b  = b_all + (size_t)i * CH * HW * HW;
        const float* f  = f_all + (size_t)i * CH * HW * HW;
        const float* mk = m_all + (size_t)i * HW * HW;
        float* outp = out + (size_t)i * CH * HW * HW;

        k_stage  <<<dim3(9, CH), 256, 0, stream>>>(b, f, bs_c, fs_c);
        k_ssq    <<<9, 256, 0, stream>>>(bs_c, ssq);
        k_norm_mm<<<9, 256, 0, stream>>>(ssq, mk, invn, mmv);
        k_w2T    <<<dim3(9, CKN), 256, 0, stream>>>(b, W2T);

        // GEMM1: D = bs^T fs : [2304 x 2304], K=128 (fp32 — precision-critical)
        gemm_tn  <<<dim3(36, 36), 256, 0, stream>>>(bs_c, fs_c, bufA, LL, LL, CH);
        k_corr   <<<dim3(9, LL), 256, 0, stream>>>(bufA, invn, bufB);
        k_fuse1  <<<dim3(9, LL), 256, 0, stream>>>(bufB, bufA);
        k_fuse2  <<<dim3(9, LL), 256, 0, stream>>>(bufA, bufB);

        k_sm1    <<<dim3(9, NCHUNK), 256, 0, stream>>>(bufB, mmv, pmax, psum);
        k_sm2    <<<9, 256, 0, stream>>>(pmax, psum, Mq, Dq);
        k_sm3T   <<<dim3(72, 72), 256, 0, stream>>>(bufB, mmv, Mq, Dq, attnT);

        // GEMM2 (bf16 MFMA): Z[q][ck] = sum_p attnT[q][p] * W2T[ck][p]
        gemm2_mfma<<<dim3(CKN / 128, LL / 128), 256, 0, stream>>>(attnT, W2T, bufA, LL, CKN, LL);
        k_out    <<<dim3(36, CH), 256, 0, stream>>>(bufA, outp);
    }
}

// Round 3
// 951.662 us; speedup vs baseline: 2.2524x; 1.2388x over previous
//
#include <hip/hip_runtime.h>
#include <hip/hip_bf16.h>
#include <math.h>

#define NS   4      // batch
#define CH   128    // channels
#define HW   96     // full-res H=W
#define GS   48     // half-res grid side
#define LL   2304   // GS*GS
#define CKN  2048   // CH*16 (4x4 taps)
#define SCALE 10.0f
#define EPSSUM 0.1152f  // 1152 * 1e-4
#define PCH2 32     // softmax p-chunk (fused into fuse2)
#define NCH2 72     // 2304/32

typedef __attribute__((ext_vector_type(8))) short short8;
typedef __attribute__((ext_vector_type(4))) float float4v;

#define GLDS16(gptr, lptr) \
    __builtin_amdgcn_global_load_lds((const __attribute__((address_space(1))) void*)(gptr), \
        (__attribute__((address_space(3))) void*)(lptr), 16, 0, 0)

// ---------------- staging ----------------

__global__ __launch_bounds__(256) void k_stage(const float* __restrict__ b, const float* __restrict__ f,
                                               float* __restrict__ bs_c, float* __restrict__ fs_c) {
    int c  = blockIdx.y;
    int rs = blockIdx.x * 256 + threadIdx.x;     // gridDim.x = 9
    int r = rs / GS, s = rs % GS;
    int src = c * HW * HW + (2 * r) * HW + 2 * s;
    bs_c[c * LL + rs] = b[src];
    fs_c[c * LL + rs] = f[src];
}

__global__ __launch_bounds__(256) void k_ssq(const float* __restrict__ bs_c, float* __restrict__ ssq) {
    int rs = blockIdx.x * 256 + threadIdx.x;
    float acc = 0.f;
    for (int c = 0; c < CH; ++c) { float v = bs_c[c * LL + rs]; acc += v * v; }
    ssq[rs] = acc;
}

__global__ __launch_bounds__(256) void k_norm_mm(const float* __restrict__ ssq, const float* __restrict__ mk,
                                                 float* __restrict__ invn, float* __restrict__ mmv) {
    int p = blockIdx.x * 256 + threadIdx.x;
    int ph = p / GS, pw = p % GS;
    float acc = EPSSUM;
    float msum = 0.f;
    for (int di = -1; di <= 1; ++di)
        for (int dj = -1; dj <= 1; ++dj) {
            int r = ph + di, s = pw + dj;
            if (r >= 0 && r < GS && s >= 0 && s < GS) {
                acc  += ssq[r * GS + s];
                msum += mk[(2 * r) * HW + 2 * s];
            }
        }
    invn[p] = 1.0f / sqrtf(acc);
    mmv[p]  = (msum / 9.0f == 1.0f) ? 1.0f : 0.0f;
}

// W2T[ck][p] = bf16( b[c, 2ph+dy-1, 2pw+dx-1] ), ck = c*16+dy*4+dx
__global__ __launch_bounds__(256) void k_w2T(const float* __restrict__ b, __hip_bfloat16* __restrict__ W2T) {
    int ck = blockIdx.y;
    int p  = blockIdx.x * 256 + threadIdx.x;     // gridDim.x = 9
    int c = ck >> 4, dy = (ck >> 2) & 3, dx = ck & 3;
    int ph = p / GS, pw = p % GS;
    int r = 2 * ph + dy - 1, s = 2 * pw + dx - 1;
    float v = 0.f;
    if (r >= 0 && r < HW && s >= 0 && s < HW) v = b[c * HW * HW + r * HW + s];
    W2T[(size_t)ck * LL + p] = __float2bfloat16(v);
}

// split fp32 [c][rs] -> transposed hi/lo bf16 [rs][c]  (hi+lo reconstructs ~17 bits)
__global__ __launch_bounds__(256) void k_split_T(const float* __restrict__ bs_c, const float* __restrict__ fs_c,
                                                 __hip_bfloat16* __restrict__ hiB, __hip_bfloat16* __restrict__ loB,
                                                 __hip_bfloat16* __restrict__ hiF, __hip_bfloat16* __restrict__ loF) {
    __shared__ float tile[32][33];
    const float* X        = blockIdx.z ? fs_c : bs_c;
    __hip_bfloat16* hi    = blockIdx.z ? hiF  : hiB;
    __hip_bfloat16* lo    = blockIdx.z ? loF  : loB;
    int r0 = blockIdx.x * 32, c0 = blockIdx.y * 32;
    int tx = threadIdx.x & 31, ty = threadIdx.x >> 5;   // ty 0..7
#pragma unroll
    for (int j = 0; j < 4; ++j)
        tile[ty + 8 * j][tx] = X[(size_t)(c0 + ty + 8 * j) * LL + r0 + tx];   // tile[c_local][r_local]
    __syncthreads();
#pragma unroll
    for (int j = 0; j < 4; ++j) {
        int rl = ty + 8 * j, cl = tx;
        float v = tile[cl][rl];
        __hip_bfloat16 h = __float2bfloat16(v);
        float resid = v - __bfloat162float(h);          // exact (Sterbenz)
        hi[(size_t)(r0 + rl) * CH + c0 + cl] = h;
        lo[(size_t)(r0 + rl) * CH + c0 + cl] = __float2bfloat16(resid);
    }
}

// ---------------- GEMM1 (split-bf16 MFMA): D[m][n] = sum_k (Ahi+Alo)[m][k]*(Bhi+Blo)[n][k] ----------------
// M=N=2304, K=128. Drops lo*lo (2^-16 rel). 128x128 tile, BK=32, 4 waves.
__global__ __launch_bounds__(256) void gemm1_mfma(const __hip_bfloat16* __restrict__ Ahi,
                                                  const __hip_bfloat16* __restrict__ Alo,
                                                  const __hip_bfloat16* __restrict__ Bhi,
                                                  const __hip_bfloat16* __restrict__ Blo,
                                                  float* __restrict__ C) {
    __shared__ __hip_bfloat16 sAh[128 * 32];
    __shared__ __hip_bfloat16 sAl[128 * 32];
    __shared__ __hip_bfloat16 sBh[128 * 32];
    __shared__ __hip_bfloat16 sBl[128 * 32];
    int t = threadIdx.x, lane = t & 63, w = t >> 6;
    int wr = w >> 1, wc = w & 1;
    int m0 = blockIdx.y * 128, n0 = blockIdx.x * 128;

    float4v acc[4][4];
#pragma unroll
    for (int i = 0; i < 4; ++i)
#pragma unroll
        for (int j = 0; j < 4; ++j) acc[i][j] = (float4v){0.f, 0.f, 0.f, 0.f};

    for (int k0 = 0; k0 < 128; k0 += 32) {
#pragma unroll
        for (int it = 0; it < 2; ++it) {
            int chunk = it * 256 + w * 64 + lane;       // 0..511, lane-contiguous per wave
            int row = chunk >> 2, part = chunk & 3;
            size_t ga = (size_t)(m0 + row) * 128 + k0 + part * 8;
            size_t gb = (size_t)(n0 + row) * 128 + k0 + part * 8;
            GLDS16(Ahi + ga, (char*)sAh + (size_t)chunk * 16);
            GLDS16(Alo + ga, (char*)sAl + (size_t)chunk * 16);
            GLDS16(Bhi + gb, (char*)sBh + (size_t)chunk * 16);
            GLDS16(Blo + gb, (char*)sBl + (size_t)chunk * 16);
        }
        __syncthreads();

        int lrow = lane & 15, lk = (lane >> 4) * 8;
        short8 ah[4], al[4], bh[4], bl[4];
#pragma unroll
        for (int i = 0; i < 4; ++i) {
            ah[i] = *reinterpret_cast<const short8*>(sAh + (wr * 64 + i * 16 + lrow) * 32 + lk);
            al[i] = *reinterpret_cast<const short8*>(sAl + (wr * 64 + i * 16 + lrow) * 32 + lk);
        }
#pragma unroll
        for (int j = 0; j < 4; ++j) {
            bh[j] = *reinterpret_cast<const short8*>(sBh + (wc * 64 + j * 16 + lrow) * 32 + lk);
            bl[j] = *reinterpret_cast<const short8*>(sBl + (wc * 64 + j * 16 + lrow) * 32 + lk);
        }
#pragma unroll
        for (int i = 0; i < 4; ++i)
#pragma unroll
            for (int j = 0; j < 4; ++j) {
                acc[i][j] = __builtin_amdgcn_mfma_f32_16x16x32_bf16(ah[i], bh[j], acc[i][j], 0, 0, 0);
                acc[i][j] = __builtin_amdgcn_mfma_f32_16x16x32_bf16(ah[i], bl[j], acc[i][j], 0, 0, 0);
                acc[i][j] = __builtin_amdgcn_mfma_f32_16x16x32_bf16(al[i], bh[j], acc[i][j], 0, 0, 0);
            }
        __syncthreads();
    }

    int col = lane & 15, rbase = (lane >> 4) * 4;
#pragma unroll
    for (int i = 0; i < 4; ++i)
#pragma unroll
        for (int j = 0; j < 4; ++j)
#pragma unroll
            for (int r = 0; r < 4; ++r) {
                int m = m0 + wr * 64 + i * 16 + rbase + r;
                int n = n0 + wc * 64 + j * 16 + col;
                C[(size_t)m * LL + n] = acc[i][j][r];
            }
}

// ---------------- GEMM2 (bf16 MFMA): C[m][n] = sum_k A[m][k]*B[n][k] ----------------
__global__ __launch_bounds__(256) void gemm2_mfma(const __hip_bfloat16* __restrict__ A,
                                                  const __hip_bfloat16* __restrict__ B,
                                                  float* __restrict__ C, int M, int N, int K) {
    __shared__ __hip_bfloat16 As[128 * 32];
    __shared__ __hip_bfloat16 Bs[128 * 32];
    int t = threadIdx.x;
    int lane = t & 63, w = t >> 6;
    int wr = w >> 1, wc = w & 1;
    int m0 = blockIdx.y * 128, n0 = blockIdx.x * 128;

    float4v acc[4][4];
#pragma unroll
    for (int i = 0; i < 4; ++i)
#pragma unroll
        for (int j = 0; j < 4; ++j) acc[i][j] = (float4v){0.f, 0.f, 0.f, 0.f};

    for (int k0 = 0; k0 < K; k0 += 32) {
#pragma unroll
        for (int it = 0; it < 2; ++it) {
            int chunk = it * 256 + w * 64 + lane;
            int row = chunk >> 2, part = chunk & 3;
            const __hip_bfloat16* ga = A + (size_t)(m0 + row) * K + k0 + part * 8;
            const __hip_bfloat16* gb = B + (size_t)(n0 + row) * K + k0 + part * 8;
            GLDS16(ga, (char*)As + (size_t)chunk * 16);
            GLDS16(gb, (char*)Bs + (size_t)chunk * 16);
        }
        __syncthreads();

        int lrow = lane & 15, lk = (lane >> 4) * 8;
        short8 afrag[4], bfrag[4];
#pragma unroll
        for (int i = 0; i < 4; ++i)
            afrag[i] = *reinterpret_cast<const short8*>(As + (wr * 64 + i * 16 + lrow) * 32 + lk);
#pragma unroll
        for (int j = 0; j < 4; ++j)
            bfrag[j] = *reinterpret_cast<const short8*>(Bs + (wc * 64 + j * 16 + lrow) * 32 + lk);
#pragma unroll
        for (int i = 0; i < 4; ++i)
#pragma unroll
            for (int j = 0; j < 4; ++j)
                acc[i][j] = __builtin_amdgcn_mfma_f32_16x16x32_bf16(afrag[i], bfrag[j], acc[i][j], 0, 0, 0);
        __syncthreads();
    }

    int col = lane & 15, rbase = (lane >> 4) * 4;
#pragma unroll
    for (int i = 0; i < 4; ++i)
#pragma unroll
        for (int j = 0; j < 4; ++j)
#pragma unroll
            for (int r = 0; r < 4; ++r) {
                int m = m0 + wr * 64 + i * 16 + rbase + r;
                int n = n0 + wc * 64 + j * 16 + col;
                C[(size_t)m * N + n] = acc[i][j][r];
            }
}

// ---------------- correlation assembly + fuses ----------------

__global__ __launch_bounds__(256) void k_corr(const float* __restrict__ D, const float* __restrict__ invn,
                                              float* __restrict__ yi) {
    int p = blockIdx.y;
    int q = blockIdx.x * 256 + threadIdx.x;
    int ph = p / GS, pw = p % GS, qh = q / GS, qw = q % GS;
    float s = 0.f;
#pragma unroll
    for (int di = -1; di <= 1; ++di) {
        int rp = ph + di, tq = qh + di;
        if (rp < 0 || rp >= GS || tq < 0 || tq >= GS) continue;
#pragma unroll
        for (int dj = -1; dj <= 1; ++dj) {
            int sp = pw + dj, uq = qw + dj;
            if (sp < 0 || sp >= GS || uq < 0 || uq >= GS) continue;
            s += D[(size_t)(rp * GS + sp) * LL + (tq * GS + uq)];
        }
    }
    yi[(size_t)p * LL + q] = invn[p] * s;
}

__global__ __launch_bounds__(256) void k_fuse1(const float* __restrict__ yi, float* __restrict__ S1) {
    int a = blockIdx.y;
    int bcol = blockIdx.x * 256 + threadIdx.x;
    float s = 0.f;
#pragma unroll
    for (int d = -1; d <= 1; ++d) {
        int aa = a + d, bb = bcol + d;
        if (aa >= 0 && aa < LL && bb >= 0 && bb < LL) s += yi[(size_t)aa * LL + bb];
    }
    S1[(size_t)a * LL + bcol] = s;
}

__device__ __forceinline__ int gmap(int x) { int hi = x / GS; int lo = x - hi * GS; return lo * GS + hi; }

// fuse2 + softmax partials: S2[p][q] + online per-(p-chunk,q) max/sum of masked logits
__global__ __launch_bounds__(256) void k_fuse2_sm(const float* __restrict__ S1, const float* __restrict__ mmv,
                                                  float* __restrict__ S2,
                                                  float* __restrict__ pmax, float* __restrict__ psum) {
    int q = blockIdx.x * 256 + threadIdx.x;
    int qh = q / GS, qw = q % GS;
    int b0 = qw * GS + qh;
    int p0 = blockIdx.y * PCH2;
    float mx = -1e30f, sm = 0.f;
    for (int i = 0; i < PCH2; ++i) {
        int p = p0 + i;
        int ph = p / GS, pw = p % GS;
        int a0 = pw * GS + ph;
        float s = 0.f;
#pragma unroll
        for (int e = -1; e <= 1; ++e) {
            int ae = a0 + e, be = b0 + e;
            if (ae >= 0 && ae < LL && be >= 0 && be < LL)
                s += S1[(size_t)gmap(ae) * LL + gmap(be)];
        }
        S2[(size_t)p * LL + q] = s;
        float lg = (mmv[p] != 0.f) ? SCALE * s : 0.f;   // masked logits are exactly 0 (matches ref)
        float nm = fmaxf(mx, lg);
        sm = sm * __expf(mx - nm) + __expf(lg - nm);
        mx = nm;
    }
    pmax[blockIdx.y * LL + q] = mx;
    psum[blockIdx.y * LL + q] = sm;
}

__global__ __launch_bounds__(256) void k_sm2(const float* __restrict__ pmax, const float* __restrict__ psum,
                                             float* __restrict__ Mq, float* __restrict__ Dq) {
    int q = blockIdx.x * 256 + threadIdx.x;
    float m0 = -1e30f, m1 = -1e30f, m2 = -1e30f, m3 = -1e30f;
#pragma unroll
    for (int ch = 0; ch < NCH2; ch += 4) {
        m0 = fmaxf(m0, pmax[(size_t)(ch + 0) * LL + q]);
        m1 = fmaxf(m1, pmax[(size_t)(ch + 1) * LL + q]);
        m2 = fmaxf(m2, pmax[(size_t)(ch + 2) * LL + q]);
        m3 = fmaxf(m3, pmax[(size_t)(ch + 3) * LL + q]);
    }
    float mx = fmaxf(fmaxf(m0, m1), fmaxf(m2, m3));
    float s0 = 0.f, s1 = 0.f, s2 = 0.f, s3 = 0.f;
#pragma unroll
    for (int ch = 0; ch < NCH2; ch += 4) {
        s0 += psum[(size_t)(ch + 0) * LL + q] * __expf(pmax[(size_t)(ch + 0) * LL + q] - mx);
        s1 += psum[(size_t)(ch + 1) * LL + q] * __expf(pmax[(size_t)(ch + 1) * LL + q] - mx);
        s2 += psum[(size_t)(ch + 2) * LL + q] * __expf(pmax[(size_t)(ch + 2) * LL + q] - mx);
        s3 += psum[(size_t)(ch + 3) * LL + q] * __expf(pmax[(size_t)(ch + 3) * LL + q] - mx);
    }
    Mq[q] = mx;
    Dq[q] = (s0 + s1) + (s2 + s3);
}

// attnT[q][p] = bf16( mmv[p] * exp(10*S2[p][q] - Mq[q]) / Dq[q] ) via 32x32 LDS transpose
__global__ __launch_bounds__(256) void k_sm3T(const float* __restrict__ S2, const float* __restrict__ mmv,
                                              const float* __restrict__ Mq, const float* __restrict__ Dq,
                                              __hip_bfloat16* __restrict__ attnT) {
    __shared__ float tile[32][33];
    int tx = threadIdx.x & 31, ty = threadIdx.x >> 5;
    int p0 = blockIdx.y * 32, q0 = blockIdx.x * 32;
    int q = q0 + tx;
    float mq = Mq[q], dq = Dq[q];
#pragma unroll
    for (int j = 0; j < 4; ++j) {
        int p = p0 + ty + 8 * j;
        float v = S2[(size_t)p * LL + q];
        float attn = (mmv[p] != 0.f) ? __expf(SCALE * v - mq) / dq : 0.f;
        tile[ty + 8 * j][tx] = attn;
    }
    __syncthreads();
#pragma unroll
    for (int j = 0; j < 4; ++j) {
        int qq = q0 + ty + 8 * j;
        attnT[(size_t)qq * LL + p0 + tx] = __float2bfloat16(tile[tx][ty + 8 * j]);
    }
}

// ---------------- output assembly ----------------
__global__ __launch_bounds__(256) void k_out(const float* __restrict__ Z, float* __restrict__ out) {
    int c  = blockIdx.y;
    int yx = blockIdx.x * 256 + threadIdx.x;     // gridDim.x = 36
    int y = yx / HW, x = yx % HW;
    int u = y >> 1, a = y & 1, v = x >> 1, w = x & 1;
    int qh1 = u + a - 1, qh2 = u + a, qw1 = v + w - 1, qw2 = v + w;
    int cb = c * 16;
    float s = 0.f;
    if (qh1 >= 0) {
        if (qw1 >= 0)  s += Z[(size_t)(qh1 * GS + qw1) * CKN + cb + (3 - a) * 4 + (3 - w)];
        if (qw2 < GS)  s += Z[(size_t)(qh1 * GS + qw2) * CKN + cb + (3 - a) * 4 + (1 - w)];
    }
    if (qh2 < GS) {
        if (qw1 >= 0)  s += Z[(size_t)(qh2 * GS + qw1) * CKN + cb + (1 - a) * 4 + (3 - w)];
        if (qw2 < GS)  s += Z[(size_t)(qh2 * GS + qw2) * CKN + cb + (1 - a) * 4 + (1 - w)];
    }
    out[(size_t)c * HW * HW + yx] = 0.25f * s;
}

// ---------------- launch ----------------

extern "C" void kernel_launch(void* const* d_in, const int* in_sizes, int n_in,
                              void* d_out, int out_size, void* d_ws, size_t ws_size,
                              hipStream_t stream) {
    const float* b_all = (const float*)d_in[0];
    const float* f_all = (const float*)d_in[1];
    const float* m_all = (const float*)d_in[2];
    float* out = (float*)d_out;
    float* ws  = (float*)d_ws;

    size_t off = 0;
    float* bs_c = ws + off; off += (size_t)CH * LL;
    float* fs_c = ws + off; off += (size_t)CH * LL;
    float* ssq  = ws + off; off += LL;
    float* invn = ws + off; off += LL;
    float* mmv  = ws + off; off += LL;
    float* Mq   = ws + off; off += LL;
    float* Dq   = ws + off; off += LL;
    float* pmax = ws + off; off += (size_t)NCH2 * LL;
    float* psum = ws + off; off += (size_t)NCH2 * LL;
    float* bufA = ws + off; off += (size_t)LL * LL;   // D -> S1 -> Z
    float* bufB = ws + off; off += (size_t)LL * LL;   // (splits) -> yi -> S2
    __hip_bfloat16* W2T   = (__hip_bfloat16*)(ws + off); off += (size_t)CKN * LL / 2;
    __hip_bfloat16* attnT = (__hip_bfloat16*)(ws + off); off += (size_t)LL * LL / 2;

    // split-bf16 operands for GEMM1, aliased into bufB (dead between k_split_T and k_corr)
    __hip_bfloat16* bsT_hi = (__hip_bfloat16*)bufB;
    __hip_bfloat16* bsT_lo = bsT_hi + (size_t)LL * CH;
    __hip_bfloat16* fsT_hi = bsT_lo + (size_t)LL * CH;
    __hip_bfloat16* fsT_lo = fsT_hi + (size_t)LL * CH;

    for (int i = 0; i < NS; ++i) {
        const float* b  = b_all + (size_t)i * CH * HW * HW;
        const float* f  = f_all + (size_t)i * CH * HW * HW;
        const float* mk = m_all + (size_t)i * HW * HW;
        float* outp = out + (size_t)i * CH * HW * HW;

        k_stage   <<<dim3(9, CH), 256, 0, stream>>>(b, f, bs_c, fs_c);
        k_ssq     <<<9, 256, 0, stream>>>(bs_c, ssq);
        k_norm_mm <<<9, 256, 0, stream>>>(ssq, mk, invn, mmv);
        k_w2T     <<<dim3(9, CKN), 256, 0, stream>>>(b, W2T);
        k_split_T <<<dim3(72, 4, 2), 256, 0, stream>>>(bs_c, fs_c, bsT_hi, bsT_lo, fsT_hi, fsT_lo);

        // GEMM1: D[p][q] = sum_c bs[p][c]*fs[q][c]  (split-bf16 MFMA, ~fp32 precision)
        gemm1_mfma<<<dim3(18, 18), 256, 0, stream>>>(bsT_hi, bsT_lo, fsT_hi, fsT_lo, bufA);
        k_corr    <<<dim3(9, LL), 256, 0, stream>>>(bufA, invn, bufB);
        k_fuse1   <<<dim3(9, LL), 256, 0, stream>>>(bufB, bufA);
        k_fuse2_sm<<<dim3(9, NCH2), 256, 0, stream>>>(bufA, mmv, bufB, pmax, psum);

        k_sm2     <<<9, 256, 0, stream>>>(pmax, psum, Mq, Dq);
        k_sm3T    <<<dim3(72, 72), 256, 0, stream>>>(bufB, mmv, Mq, Dq, attnT);

        // GEMM2 (bf16 MFMA): Z[q][ck] = sum_p attnT[q][p] * W2T[ck][p]
        gemm2_mfma<<<dim3(CKN / 128, LL / 128), 256, 0, stream>>>(attnT, W2T, bufA, LL, CKN, LL);
        k_out     <<<dim3(36, CH), 256, 0, stream>>>(bufA, outp);
    }
}